// Round 8
// baseline (246.926 us; speedup 1.0000x reference)
//
#include <hip/hip_runtime.h>

#define NB 4
#define NC 256
#define ND 46
#define NH 55
#define NW 46
#define NN (ND*NH*NW)        // 116380
#define NVEC (NN/4)          // 29095
#define NR 200
#define NL 201
#define NPLANES (NB*NC)      // 1024
#define NFEAT (NB*NR*NC)     // 204800
#define MROI 256             // padded roi rows (only tiles 0..12 stored)
#define CHV 128              // voxels per staged chunk (4 k-steps of 32)
#define NCH 909              // full chunks: 909*128 = 116352
#define TAILF4 7             // tail float4s: voxels 116352..116379 (28)
#define LROWD 68             // fm row stride in dwords (256B data + 16B pad)
#define AOFFD (64*LROWD)     // atlas region offset in dwords (4352)
#define BUFD (AOFFD + 128)   // dwords per buffer (4480 = 17920 B)

typedef __attribute__((ext_vector_type(8))) short bf16x8;
typedef __attribute__((ext_vector_type(4))) float f32x4;

union BU { uint4 u; bf16x8 v; };

// two f32 -> packed bf16 pair (round-half-up, 2 add + 1 v_perm)
__device__ __forceinline__ unsigned pkbf(float x, float y) {
    unsigned ux = __float_as_uint(x) + 0x8000u;
    unsigned uy = __float_as_uint(y) + 0x8000u;
    return __builtin_amdgcn_perm(uy, ux, 0x07060302u);
}
// packed one-hot pair: lo match -> 0x3F80 (bf16 1.0), hi match -> 0x3F800000
__device__ __forceinline__ unsigned oh2(int l0, int l1, int c) {
    return (l0 == c ? 0x3F80u : 0u) | (l1 == c ? 0x3F800000u : 0u);
}
__device__ __forceinline__ bf16x8 mkA(const int4& la, const int4& lb, int c) {
    union { unsigned u[4]; bf16x8 v; } x;
    x.u[0] = oh2(la.x, la.y, c);
    x.u[1] = oh2(la.z, la.w, c);
    x.u[2] = oh2(lb.x, lb.y, c);
    x.u[3] = oh2(lb.z, lb.w, c);
    return x.v;
}

// ---------------- counts: histogram of atlas labels ----------------
__global__ __launch_bounds__(256) void roi_count(const int* __restrict__ atlas,
                                                 float* __restrict__ counts) {
    __shared__ float h[NL];
    const int tid = threadIdx.x;
    for (int i = tid; i < NL; i += 256) h[i] = 0.0f;
    __syncthreads();
    const int iv = blockIdx.x * 256 + tid;
    if (iv < NVEC) {
        int4 lab = ((const int4*)atlas)[iv];
        atomicAdd(&h[lab.x], 1.0f);
        atomicAdd(&h[lab.y], 1.0f);
        atomicAdd(&h[lab.z], 1.0f);
        atomicAdd(&h[lab.w], 1.0f);
    }
    __syncthreads();
    for (int i = tid; i < NL; i += 256) {
        float v = h[i];
        if (i > 0 && v != 0.0f) atomicAdd(&counts[i - 1], v);
    }
}

// ---------------- main: double-buffered LDS-staged one-hot MFMA GEMM ----------
// grid = (KCH, NPLANES/64); block = 256 (4 waves).
// Per 128-voxel chunk: coalesced stage fm f32->bf16 + atlas into LDS
// (double-buffered, ONE barrier/chunk), then 4 k-steps of
// (atlas ds_read + 4x ds_read_b128 B + one-hot A build + MFMA).
// Wave 3 computes only roi-tile 12 (rois 192..207); tiles 13-15 are padding.
__global__ __launch_bounds__(256, 4) void roi_accum_db(const float* __restrict__ fm,
                                                       const int* __restrict__ atlas,
                                                       float* __restrict__ partials,
                                                       const int SPl) {
    __shared__ unsigned lds[2][BUFD];   // 2 x 17920 B
    const int tid  = threadIdx.x;
    const int wave = tid >> 6;
    const int lane = tid & 63;
    const int g    = lane >> 4;
    const int n    = lane & 15;
    const int pb   = blockIdx.y * 64;
    const int chunk = blockIdx.x;

    const int sr = tid >> 2;      // staging plane 0..63
    const int sc = tid & 3;       // staging 32-voxel quarter
    const float4* sf = (const float4*)(fm + (size_t)(pb + sr) * NN);
    const int4* at4 = (const int4*)atlas;

    f32x4 acc[4][4];
    #pragma unroll
    for (int t = 0; t < 4; ++t)
        #pragma unroll
        for (int p = 0; p < 4; ++p)
            acc[t][p] = (f32x4){0.f, 0.f, 0.f, 0.f};

    const int t0    = wave * 4;
    const int cbase = t0 * 16 + n + 1;
    const int NT    = (wave == 3) ? 1 : 4;   // tiles 13..15 are padding

    const int c0 = chunk * SPl;
    const int c1 = min(c0 + SPl, NCH);

    float4 L[8];
    int4   LA;
    int buf = 0;

    // ---- prologue: stage chunk c0 into lds[0], prefetch c0+1 ----
    if (c0 < c1) {
        const float4* p = sf + (size_t)c0 * 32 + sc * 8;
        #pragma unroll
        for (int j = 0; j < 8; ++j) L[j] = p[j];
        if (tid < 32) LA = at4[c0 * 32 + tid];

        unsigned* w = &lds[0][sr * LROWD + sc * 16];
        #pragma unroll
        for (int i = 0; i < 4; ++i)
            ((uint4*)w)[i] = make_uint4(pkbf(L[2*i].x, L[2*i].y),
                                        pkbf(L[2*i].z, L[2*i].w),
                                        pkbf(L[2*i+1].x, L[2*i+1].y),
                                        pkbf(L[2*i+1].z, L[2*i+1].w));
        if (tid < 32)
            *(int4*)&lds[0][AOFFD + tid * 4] = LA;

        if (c0 + 1 < c1) {
            const float4* q = sf + (size_t)(c0 + 1) * 32 + sc * 8;
            #pragma unroll
            for (int j = 0; j < 8; ++j) L[j] = q[j];
            if (tid < 32) LA = at4[(c0 + 1) * 32 + tid];
        }
    }
    __syncthreads();

    // ---- main loop: 1 barrier per chunk ----
    for (int ch = c0; ch < c1; ++ch, buf ^= 1) {
        if (ch + 1 < c1) {
            // write prefetched chunk ch+1 into the other buffer
            unsigned* w = &lds[buf ^ 1][sr * LROWD + sc * 16];
            #pragma unroll
            for (int i = 0; i < 4; ++i)
                ((uint4*)w)[i] = make_uint4(pkbf(L[2*i].x, L[2*i].y),
                                            pkbf(L[2*i].z, L[2*i].w),
                                            pkbf(L[2*i+1].x, L[2*i+1].y),
                                            pkbf(L[2*i+1].z, L[2*i+1].w));
            if (tid < 32)
                *(int4*)&lds[buf ^ 1][AOFFD + tid * 4] = LA;
            if (ch + 2 < c1) {
                const float4* q = sf + (size_t)(ch + 2) * 32 + sc * 8;
                #pragma unroll
                for (int j = 0; j < 8; ++j) L[j] = q[j];
                if (tid < 32) LA = at4[(ch + 2) * 32 + tid];
            }
        }
        #pragma unroll
        for (int ks = 0; ks < 4; ++ks) {
            const unsigned* ab = &lds[buf][AOFFD + (ks * 8 + 2 * g) * 4];
            int4 la = *(const int4*)ab;
            int4 lb = *(const int4*)(ab + 4);
            BU B0, B1, B2, B3;
            B0.u = *(const uint4*)&lds[buf][(0 * 16 + n) * LROWD + ks * 16 + g * 4];
            B1.u = *(const uint4*)&lds[buf][(1 * 16 + n) * LROWD + ks * 16 + g * 4];
            B2.u = *(const uint4*)&lds[buf][(2 * 16 + n) * LROWD + ks * 16 + g * 4];
            B3.u = *(const uint4*)&lds[buf][(3 * 16 + n) * LROWD + ks * 16 + g * 4];
            #pragma unroll
            for (int t = 0; t < 4; ++t) {
                if (t < NT) {
                    bf16x8 A = mkA(la, lb, cbase + 16 * t);
                    acc[t][0] = __builtin_amdgcn_mfma_f32_16x16x32_bf16(A, B0.v, acc[t][0], 0, 0, 0);
                    acc[t][1] = __builtin_amdgcn_mfma_f32_16x16x32_bf16(A, B1.v, acc[t][1], 0, 0, 0);
                    acc[t][2] = __builtin_amdgcn_mfma_f32_16x16x32_bf16(A, B2.v, acc[t][2], 0, 0, 0);
                    acc[t][3] = __builtin_amdgcn_mfma_f32_16x16x32_bf16(A, B3.v, acc[t][3], 0, 0, 0);
                }
            }
        }
        __syncthreads();
    }

    // ---- tail: 28 voxels, handled by the block owning the last chunk ----
    if (c0 < NCH && c1 == NCH) {
        const float4 zf = {0.f, 0.f, 0.f, 0.f};
        unsigned* w = &lds[buf][sr * LROWD + sc * 16];
        #pragma unroll
        for (int i = 0; i < 4; ++i) {
            const int j0 = 2 * i, j1 = 2 * i + 1;
            float4 va = (sc == 0 && j0 < TAILF4) ? sf[(size_t)NCH * 32 + sc * 8 + j0] : zf;
            float4 vb = (sc == 0 && j1 < TAILF4) ? sf[(size_t)NCH * 32 + sc * 8 + j1] : zf;
            ((uint4*)w)[i] = make_uint4(pkbf(va.x, va.y), pkbf(va.z, va.w),
                                        pkbf(vb.x, vb.y), pkbf(vb.z, vb.w));
        }
        if (tid < 32) {
            int4 a = (tid < TAILF4) ? at4[NCH * 32 + tid] : (int4){0, 0, 0, 0};
            *(int4*)&lds[buf][AOFFD + tid * 4] = a;
        }
        __syncthreads();
        const unsigned* ab = &lds[buf][AOFFD + (2 * g) * 4];
        int4 la = *(const int4*)ab;
        int4 lb = *(const int4*)(ab + 4);
        BU B0, B1, B2, B3;
        B0.u = *(const uint4*)&lds[buf][(0 * 16 + n) * LROWD + g * 4];
        B1.u = *(const uint4*)&lds[buf][(1 * 16 + n) * LROWD + g * 4];
        B2.u = *(const uint4*)&lds[buf][(2 * 16 + n) * LROWD + g * 4];
        B3.u = *(const uint4*)&lds[buf][(3 * 16 + n) * LROWD + g * 4];
        #pragma unroll
        for (int t = 0; t < 4; ++t) {
            if (t < NT) {
                bf16x8 A = mkA(la, lb, cbase + 16 * t);
                acc[t][0] = __builtin_amdgcn_mfma_f32_16x16x32_bf16(A, B0.v, acc[t][0], 0, 0, 0);
                acc[t][1] = __builtin_amdgcn_mfma_f32_16x16x32_bf16(A, B1.v, acc[t][1], 0, 0, 0);
                acc[t][2] = __builtin_amdgcn_mfma_f32_16x16x32_bf16(A, B2.v, acc[t][2], 0, 0, 0);
                acc[t][3] = __builtin_amdgcn_mfma_f32_16x16x32_bf16(A, B3.v, acc[t][3], 0, 0, 0);
            }
        }
    }

    // ---- store: partials[chunk][roi(256, tiles<=12)][plane(1024)] ----
    // D layout: col = lane&15, row = 4*(lane>>4)+i
    float* pc = partials + (size_t)chunk * (MROI * NPLANES);
    const int rbase = 4 * g;
    #pragma unroll
    for (int t = 0; t < 4; ++t) {
        if (t < NT) {
            #pragma unroll
            for (int p = 0; p < 4; ++p)
                #pragma unroll
                for (int i = 0; i < 4; ++i)
                    pc[(size_t)((t0 + t) * 16 + rbase + i) * NPLANES + (pb + 16 * p + n)] = acc[t][p][i];
        }
    }
}

// ---------------- finalize: reduce chunks + divide + mask ----------------
__global__ __launch_bounds__(256) void roi_final2(const float* __restrict__ partials,
                                                  const float* __restrict__ counts,
                                                  float* __restrict__ out,
                                                  const int kch) {
    const int j = blockIdx.x * 256 + threadIdx.x;
    if (j < NFEAT) {
        const int c = j & (NC - 1);
        const int r = (j >> 8) % NR;
        const int b = j / (NR * NC);
        const int plane = b * NC + c;
        float s = 0.0f;
        for (int ch = 0; ch < kch; ++ch)
            s += partials[((size_t)ch * MROI + r) * NPLANES + plane];
        const float cnt = counts[r];
        out[j] = (cnt > 0.0f) ? s / cnt : 0.0f;
    } else if (j < NFEAT + NB * NR) {
        const int r = (j - NFEAT) % NR;
        out[j] = (counts[r] > 0.0f) ? 1.0f : 0.0f;
    }
}

extern "C" void kernel_launch(void* const* d_in, const int* in_sizes, int n_in,
                              void* d_out, int out_size, void* d_ws, size_t ws_size,
                              hipStream_t stream) {
    const float* fm    = (const float*)d_in[0];
    const int*   atlas = (const int*)d_in[1];
    float*       out   = (float*)d_out;

    float* counts   = (float*)d_ws;     // 256 floats
    float* partials = counts + 256;     // kch * MROI * NPLANES floats

    int kch = 64;
    while (kch > 16 &&
           ws_size < 1024 + (size_t)kch * MROI * NPLANES * sizeof(float))
        kch >>= 1;
    const int spl = (NCH + kch - 1) / kch;

    hipMemsetAsync(counts, 0, NR * sizeof(float), stream);

    roi_count<<<(NVEC + 255) / 256, 256, 0, stream>>>(atlas, counts);

    roi_accum_db<<<dim3(kch, NPLANES / 64), 256, 0, stream>>>(fm, atlas, partials, spl);

    const int total = NFEAT + NB * NR;
    roi_final2<<<(total + 255) / 256, 256, 0, stream>>>(partials, counts, out, kch);
}

// Round 9
// 192.543 us; speedup vs baseline: 1.2824x; 1.2824x over previous
//
#include <hip/hip_runtime.h>

#define NB 4
#define NC 256
#define ND 46
#define NH 55
#define NW 46
#define NN (ND*NH*NW)        // 116380
#define NVEC (NN/4)          // 29095
#define NR 200
#define NL 201
#define NPLANES (NB*NC)      // 1024
#define NFEAT (NB*NR*NC)     // 204800
#define MROI 256             // padded roi rows (only tiles 0..12 stored)
#define CHV 192              // voxels per chunk = 6 k-steps of 32
#define F4PC 48              // float4 per plane per chunk
#define NCH 606              // 606*192 = 116352
#define TAILF4 7             // tail float4s: voxels 116352..116379 (28)
#define LROWD 100            // LDS row stride in dwords (96 data + 4 pad)
#define AOFFD (64*LROWD)     // atlas region offset (6400 dwords)
#define BUFD (AOFFD + 200)   // 6600 dwords = 26400 B

typedef __attribute__((ext_vector_type(8))) short bf16x8;
typedef __attribute__((ext_vector_type(4))) float f32x4;

union BU { uint4 u; bf16x8 v; };

// two f32 -> packed bf16 pair (round-half-up, 2 add + 1 v_perm)
__device__ __forceinline__ unsigned pkbf(float x, float y) {
    unsigned ux = __float_as_uint(x) + 0x8000u;
    unsigned uy = __float_as_uint(y) + 0x8000u;
    return __builtin_amdgcn_perm(uy, ux, 0x07060302u);
}
// packed one-hot pair: lo match -> 0x3F80 (bf16 1.0), hi match -> 0x3F800000
__device__ __forceinline__ unsigned oh2(int l0, int l1, int c) {
    return (l0 == c ? 0x3F80u : 0u) | (l1 == c ? 0x3F800000u : 0u);
}
__device__ __forceinline__ bf16x8 mkA(const int4& la, const int4& lb, int c) {
    union { unsigned u[4]; bf16x8 v; } x;
    x.u[0] = oh2(la.x, la.y, c);
    x.u[1] = oh2(la.z, la.w, c);
    x.u[2] = oh2(lb.x, lb.y, c);
    x.u[3] = oh2(lb.z, lb.w, c);
    return x.v;
}

// ---------------- counts: histogram of atlas labels ----------------
__global__ __launch_bounds__(256) void roi_count(const int* __restrict__ atlas,
                                                 float* __restrict__ counts) {
    __shared__ float h[NL];
    const int tid = threadIdx.x;
    for (int i = tid; i < NL; i += 256) h[i] = 0.0f;
    __syncthreads();
    const int iv = blockIdx.x * 256 + tid;
    if (iv < NVEC) {
        int4 lab = ((const int4*)atlas)[iv];
        atomicAdd(&h[lab.x], 1.0f);
        atomicAdd(&h[lab.y], 1.0f);
        atomicAdd(&h[lab.z], 1.0f);
        atomicAdd(&h[lab.w], 1.0f);
    }
    __syncthreads();
    for (int i = tid; i < NL; i += 256) {
        float v = h[i];
        if (i > 0 && v != 0.0f) atomicAdd(&counts[i - 1], v);
    }
}

// ---------------- main: single-buffer LDS-staged one-hot MFMA GEMM ----------
// grid = (KCH, 16); block = 256 (4 waves). Block C-tile: 256 rois x 64 planes.
// Per 192-voxel chunk: stage fm f32->bf16 (768 B/plane contiguous) + atlas
// into LDS, barrier, 6 k-steps of (LDS atlas + 4x ds_read_b128 B + one-hot A
// + MFMA), barrier. Wave 3 computes only roi-tile 12 (rois 192..207).
__global__ __launch_bounds__(256, 4) void roi_accum_v9(const float* __restrict__ fm,
                                                       const int* __restrict__ atlas,
                                                       float* __restrict__ partials) {
    __shared__ unsigned lds[BUFD];
    const int tid  = threadIdx.x;
    const int wave = tid >> 6;
    const int lane = tid & 63;
    const int g    = lane >> 4;
    const int n    = lane & 15;
    const int pb   = blockIdx.y * 64;
    const int x    = blockIdx.x;
    const int gx   = gridDim.x;

    // balanced chunk split: base = NCH/gx, first rem blocks get one extra
    const int base = NCH / gx;
    const int rem  = NCH % gx;
    const int c0 = x * base + min(x, rem);
    const int c1 = c0 + base + (x < rem ? 1 : 0);

    const int sr = tid >> 2;      // staging plane 0..63
    const int sc = tid & 3;       // staging quarter (12 float4 each)
    const float4* sf = (const float4*)(fm + (size_t)(pb + sr) * NN);
    const int4* at4 = (const int4*)atlas;

    f32x4 acc[4][4];
    #pragma unroll
    for (int t = 0; t < 4; ++t)
        #pragma unroll
        for (int p = 0; p < 4; ++p)
            acc[t][p] = (f32x4){0.f, 0.f, 0.f, 0.f};

    const int t0    = wave * 4;
    const int cbase = t0 * 16 + n + 1;
    const int NT    = (wave == 3) ? 1 : 4;   // tiles 13..15 are roi padding

    unsigned* wb = &lds[sr * LROWD + sc * 24];

    for (int ch = c0; ch < c1; ++ch) {
        if (ch > c0) __syncthreads();        // prior chunk's reads done
        // ---- stage fm: 3 groups of 4 float4 (thread covers 192 B contig) ----
        const float4* sp = sf + (size_t)ch * F4PC + sc * 12;
        #pragma unroll
        for (int k = 0; k < 3; ++k) {
            float4 v0 = sp[4 * k + 0];
            float4 v1 = sp[4 * k + 1];
            float4 v2 = sp[4 * k + 2];
            float4 v3 = sp[4 * k + 3];
            ((uint4*)(wb + 8 * k))[0]     = make_uint4(pkbf(v0.x, v0.y), pkbf(v0.z, v0.w),
                                                       pkbf(v1.x, v1.y), pkbf(v1.z, v1.w));
            ((uint4*)(wb + 8 * k + 4))[0] = make_uint4(pkbf(v2.x, v2.y), pkbf(v2.z, v2.w),
                                                       pkbf(v3.x, v3.y), pkbf(v3.z, v3.w));
        }
        if (tid < 48)
            *(int4*)&lds[AOFFD + tid * 4] = at4[ch * 48 + tid];
        __syncthreads();                     // tile visible
        // ---- consume: 6 k-steps ----
        #pragma unroll
        for (int ks = 0; ks < 6; ++ks) {
            int4 la = *(const int4*)&lds[AOFFD + ks * 32 + 8 * g];
            int4 lb = *(const int4*)&lds[AOFFD + ks * 32 + 8 * g + 4];
            BU B0, B1, B2, B3;
            B0.u = *(const uint4*)&lds[(0 * 16 + n) * LROWD + ks * 16 + g * 4];
            B1.u = *(const uint4*)&lds[(1 * 16 + n) * LROWD + ks * 16 + g * 4];
            B2.u = *(const uint4*)&lds[(2 * 16 + n) * LROWD + ks * 16 + g * 4];
            B3.u = *(const uint4*)&lds[(3 * 16 + n) * LROWD + ks * 16 + g * 4];
            #pragma unroll
            for (int t = 0; t < 4; ++t) {
                if (t < NT) {
                    bf16x8 A = mkA(la, lb, cbase + 16 * t);
                    acc[t][0] = __builtin_amdgcn_mfma_f32_16x16x32_bf16(A, B0.v, acc[t][0], 0, 0, 0);
                    acc[t][1] = __builtin_amdgcn_mfma_f32_16x16x32_bf16(A, B1.v, acc[t][1], 0, 0, 0);
                    acc[t][2] = __builtin_amdgcn_mfma_f32_16x16x32_bf16(A, B2.v, acc[t][2], 0, 0, 0);
                    acc[t][3] = __builtin_amdgcn_mfma_f32_16x16x32_bf16(A, B3.v, acc[t][3], 0, 0, 0);
                }
            }
        }
    }

    // ---- tail: 28 voxels, owned by the block whose range ends at NCH ----
    if (c1 == NCH && c0 < c1) {
        const float4 zf = {0.f, 0.f, 0.f, 0.f};
        __syncthreads();                     // prior reads done
        #pragma unroll
        for (int k = 0; k < 3; ++k) {
            const int j0 = sc * 12 + 4 * k;
            float4 v0 = (j0 + 0 < TAILF4) ? sf[(size_t)NCH * F4PC + j0 + 0] : zf;
            float4 v1 = (j0 + 1 < TAILF4) ? sf[(size_t)NCH * F4PC + j0 + 1] : zf;
            float4 v2 = (j0 + 2 < TAILF4) ? sf[(size_t)NCH * F4PC + j0 + 2] : zf;
            float4 v3 = (j0 + 3 < TAILF4) ? sf[(size_t)NCH * F4PC + j0 + 3] : zf;
            ((uint4*)(wb + 8 * k))[0]     = make_uint4(pkbf(v0.x, v0.y), pkbf(v0.z, v0.w),
                                                       pkbf(v1.x, v1.y), pkbf(v1.z, v1.w));
            ((uint4*)(wb + 8 * k + 4))[0] = make_uint4(pkbf(v2.x, v2.y), pkbf(v2.z, v2.w),
                                                       pkbf(v3.x, v3.y), pkbf(v3.z, v3.w));
        }
        if (tid < 48) {
            int4 a = (tid < TAILF4) ? at4[NCH * 48 + tid] : (int4){0, 0, 0, 0};
            *(int4*)&lds[AOFFD + tid * 4] = a;
        }
        __syncthreads();
        int4 la = *(const int4*)&lds[AOFFD + 8 * g];
        int4 lb = *(const int4*)&lds[AOFFD + 8 * g + 4];
        BU B0, B1, B2, B3;
        B0.u = *(const uint4*)&lds[(0 * 16 + n) * LROWD + g * 4];
        B1.u = *(const uint4*)&lds[(1 * 16 + n) * LROWD + g * 4];
        B2.u = *(const uint4*)&lds[(2 * 16 + n) * LROWD + g * 4];
        B3.u = *(const uint4*)&lds[(3 * 16 + n) * LROWD + g * 4];
        #pragma unroll
        for (int t = 0; t < 4; ++t) {
            if (t < NT) {
                bf16x8 A = mkA(la, lb, cbase + 16 * t);
                acc[t][0] = __builtin_amdgcn_mfma_f32_16x16x32_bf16(A, B0.v, acc[t][0], 0, 0, 0);
                acc[t][1] = __builtin_amdgcn_mfma_f32_16x16x32_bf16(A, B1.v, acc[t][1], 0, 0, 0);
                acc[t][2] = __builtin_amdgcn_mfma_f32_16x16x32_bf16(A, B2.v, acc[t][2], 0, 0, 0);
                acc[t][3] = __builtin_amdgcn_mfma_f32_16x16x32_bf16(A, B3.v, acc[t][3], 0, 0, 0);
            }
        }
    }

    // ---- store: partials[chunk][roi(256, tiles 0..12)][plane(1024)] ----
    // D layout: col = lane&15, row = 4*(lane>>4)+i
    float* pc = partials + (size_t)x * (MROI * NPLANES);
    const int rbase = 4 * g;
    #pragma unroll
    for (int t = 0; t < 4; ++t) {
        if (t < NT) {
            #pragma unroll
            for (int p = 0; p < 4; ++p)
                #pragma unroll
                for (int i = 0; i < 4; ++i)
                    pc[(size_t)((t0 + t) * 16 + rbase + i) * NPLANES + (pb + 16 * p + n)] = acc[t][p][i];
        }
    }
}

// ---------------- finalize: reduce chunks + divide + mask ----------------
__global__ __launch_bounds__(256) void roi_final2(const float* __restrict__ partials,
                                                  const float* __restrict__ counts,
                                                  float* __restrict__ out,
                                                  const int kch) {
    const int j = blockIdx.x * 256 + threadIdx.x;
    if (j < NFEAT) {
        const int c = j & (NC - 1);
        const int r = (j >> 8) % NR;
        const int b = j / (NR * NC);
        const int plane = b * NC + c;
        float s = 0.0f;
        for (int ch = 0; ch < kch; ++ch)
            s += partials[((size_t)ch * MROI + r) * NPLANES + plane];
        const float cnt = counts[r];
        out[j] = (cnt > 0.0f) ? s / cnt : 0.0f;
    } else if (j < NFEAT + NB * NR) {
        const int r = (j - NFEAT) % NR;
        out[j] = (counts[r] > 0.0f) ? 1.0f : 0.0f;
    }
}

extern "C" void kernel_launch(void* const* d_in, const int* in_sizes, int n_in,
                              void* d_out, int out_size, void* d_ws, size_t ws_size,
                              hipStream_t stream) {
    const float* fm    = (const float*)d_in[0];
    const int*   atlas = (const int*)d_in[1];
    float*       out   = (float*)d_out;

    float* counts   = (float*)d_ws;     // 256 floats
    float* partials = counts + 256;     // kch * MROI * NPLANES floats

    int kch = 64;
    while (kch > 16 &&
           ws_size < 1024 + (size_t)kch * MROI * NPLANES * sizeof(float))
        kch >>= 1;

    hipMemsetAsync(counts, 0, NR * sizeof(float), stream);

    roi_count<<<(NVEC + 255) / 256, 256, 0, stream>>>(atlas, counts);

    roi_accum_v9<<<dim3(kch, 16), 256, 0, stream>>>(fm, atlas, partials);

    const int total = NFEAT + NB * NR;
    roi_final2<<<(total + 255) / 256, 256, 0, stream>>>(partials, counts, out, kch);
}

// Round 10
// 134.945 us; speedup vs baseline: 1.8298x; 1.4268x over previous
//
#include <hip/hip_runtime.h>

#define NB 4
#define NC 256
#define NN 116380
#define NVEC (NN/4)          // 29095
#define NR 200
#define NL 201
#define NPLANES (NB*NC)      // 1024
#define NFEAT (NB*NR*NC)     // 204800
#define MROI 256             // padded roi rows (tiles 13..15 never stored)
#define CHV 64               // voxels per chunk (2 k-steps of 32)
#define NCH 1818             // full chunks: 1818*64 = 116352
#define NTAIL 28             // tail voxels
#define AOFFD 4096           // atlas offset (dwords) within a buffer
#define BUFD 4160            // 4096 fm f32 + 64 atlas
#define NBUF 3               // triple buffer -> depth-2 async pipeline

typedef __attribute__((ext_vector_type(8))) short bf16x8;
typedef __attribute__((ext_vector_type(4))) float f32x4;

union BU { uint4 u; bf16x8 v; };

// two f32 -> packed bf16 pair (round-half-up, 2 add + 1 v_perm)
__device__ __forceinline__ unsigned pkbf(float x, float y) {
    unsigned ux = __float_as_uint(x) + 0x8000u;
    unsigned uy = __float_as_uint(y) + 0x8000u;
    return __builtin_amdgcn_perm(uy, ux, 0x07060302u);
}
// packed one-hot pair: lo match -> 0x3F80 (bf16 1.0), hi match -> 0x3F800000
__device__ __forceinline__ unsigned oh2(int l0, int l1, int c) {
    return (l0 == c ? 0x3F80u : 0u) | (l1 == c ? 0x3F800000u : 0u);
}
__device__ __forceinline__ bf16x8 mkA(const int4& la, const int4& lb, int c) {
    union { unsigned u[4]; bf16x8 v; } x;
    x.u[0] = oh2(la.x, la.y, c);
    x.u[1] = oh2(la.z, la.w, c);
    x.u[2] = oh2(lb.x, lb.y, c);
    x.u[3] = oh2(lb.z, lb.w, c);
    return x.v;
}

// ---------------- counts: histogram of atlas labels ----------------
__global__ __launch_bounds__(256) void roi_count(const int* __restrict__ atlas,
                                                 float* __restrict__ counts) {
    __shared__ float h[NL];
    const int tid = threadIdx.x;
    for (int i = tid; i < NL; i += 256) h[i] = 0.0f;
    __syncthreads();
    const int iv = blockIdx.x * 256 + tid;
    if (iv < NVEC) {
        int4 lab = ((const int4*)atlas)[iv];
        atomicAdd(&h[lab.x], 1.0f);
        atomicAdd(&h[lab.y], 1.0f);
        atomicAdd(&h[lab.z], 1.0f);
        atomicAdd(&h[lab.w], 1.0f);
    }
    __syncthreads();
    for (int i = tid; i < NL; i += 256) {
        float v = h[i];
        if (i > 0 && v != 0.0f) atomicAdd(&counts[i - 1], v);
    }
}

// ---------------- main: async global_load_lds pipelined MFMA GEMM ----------
// grid = (KCH, 16); block = 256 (4 waves). Block C-tile: 256 rois x 64 planes.
// f32 tile [64 rows][64 cols] staged straight to LDS via global_load_lds
// (linear dest; source col pre-swizzled: col ^= (row&7)<<2). Triple buffer,
// depth-2 counted-vmcnt pipeline, raw s_barrier (no vmcnt(0) drain mid-loop).
// bf16 convert at consume. Wave 3 computes only roi-tile 12.
__global__ __launch_bounds__(256, 3) void roi_accum_async(const float* __restrict__ fm,
                                                          const int* __restrict__ atlas,
                                                          float* __restrict__ partials) {
    __shared__ unsigned lds[NBUF * BUFD];   // 49,920 B
    const int tid  = threadIdx.x;
    const int wave = tid >> 6;
    const int lane = tid & 63;
    const int g    = lane >> 4;
    const int n    = lane & 15;
    const int pb   = blockIdx.y * 64;
    const int x    = blockIdx.x;
    const int gx   = gridDim.x;

    const int base = NCH / gx, rem = NCH % gx;
    const int c0 = x * base + min(x, rem);
    const int c1 = c0 + base + (x < rem ? 1 : 0);

    f32x4 acc[4][4];
    #pragma unroll
    for (int t = 0; t < 4; ++t)
        #pragma unroll
        for (int p = 0; p < 4; ++p)
            acc[t][p] = (f32x4){0.f, 0.f, 0.f, 0.f};

    const int t0    = wave * 4;
    const int cbase = t0 * 16 + n + 1;
    const int NT    = (wave == 3) ? 1 : 4;    // roi-tiles 13..15 are padding

    // ---- async stage of one chunk into buffer b (5 loads/wave) ----
    auto STAGE = [&](int ch, int b) {
        #pragma unroll
        for (int j = 0; j < 4; ++j) {
            const int row  = wave * 16 + j * 4 + (lane >> 4);
            const int colp = (lane & 15) * 4;                  // stored col
            const int col  = colp ^ ((row & 7) << 2);          // source col
            const float* gp = fm + (size_t)(pb + row) * NN + ch * CHV + col;
            unsigned* lp = &lds[b * BUFD + (wave * 4 + j) * 256];
            __builtin_amdgcn_global_load_lds(
                (const __attribute__((address_space(1))) unsigned*)gp,
                (__attribute__((address_space(3))) unsigned*)lp, 16, 0, 0);
        }
        const int* ga = atlas + ch * CHV + lane;               // all waves dup (same data)
        __builtin_amdgcn_global_load_lds(
            (const __attribute__((address_space(1))) unsigned*)ga,
            (__attribute__((address_space(3))) unsigned*)&lds[b * BUFD + AOFFD], 4, 0, 0);
    };

    // ---- consume one k-step (32 voxels) from buffer b ----
    auto CONSUME_KS = [&](int b, int ks) {
        const unsigned* ap = &lds[b * BUFD + AOFFD + ks * 32 + 8 * g];
        int4 la = *(const int4*)ap;
        int4 lb = *(const int4*)(ap + 4);
        BU Bp[4];
        #pragma unroll
        for (int p = 0; p < 4; ++p) {
            const int row = p * 16 + n;
            const int xr  = (row & 7) << 2;
            const int cb  = ks * 32 + g * 8;
            f32x4 f0 = *(const f32x4*)&lds[b * BUFD + row * 64 + (cb ^ xr)];
            f32x4 f1 = *(const f32x4*)&lds[b * BUFD + row * 64 + ((cb + 4) ^ xr)];
            Bp[p].u = make_uint4(pkbf(f0[0], f0[1]), pkbf(f0[2], f0[3]),
                                 pkbf(f1[0], f1[1]), pkbf(f1[2], f1[3]));
        }
        #pragma unroll
        for (int t = 0; t < 4; ++t) {
            if (t < NT) {
                bf16x8 A = mkA(la, lb, cbase + 16 * t);
                acc[t][0] = __builtin_amdgcn_mfma_f32_16x16x32_bf16(A, Bp[0].v, acc[t][0], 0, 0, 0);
                acc[t][1] = __builtin_amdgcn_mfma_f32_16x16x32_bf16(A, Bp[1].v, acc[t][1], 0, 0, 0);
                acc[t][2] = __builtin_amdgcn_mfma_f32_16x16x32_bf16(A, Bp[2].v, acc[t][2], 0, 0, 0);
                acc[t][3] = __builtin_amdgcn_mfma_f32_16x16x32_bf16(A, Bp[3].v, acc[t][3], 0, 0, 0);
            }
        }
    };

    // ---- prologue: fill the pipeline (depth 2) ----
    if (c0 + 0 < c1) STAGE(c0 + 0, 0);
    if (c0 + 1 < c1) STAGE(c0 + 1, 1);
    if (c0 + 2 < c1) STAGE(c0 + 2, 2);

    int b = 0;
    for (int c = c0; c < c1; ++c) {
        const int ahead = min(c1, c + 3) - (c + 1);   // staged chunks beyond c
        if (ahead >= 2)      asm volatile("s_waitcnt vmcnt(10)" ::: "memory");
        else if (ahead == 1) asm volatile("s_waitcnt vmcnt(5)" ::: "memory");
        else                 asm volatile("s_waitcnt vmcnt(0)" ::: "memory");
        __builtin_amdgcn_s_barrier();                 // chunk c resident for all waves
        __builtin_amdgcn_sched_barrier(0);
        CONSUME_KS(b, 0);
        CONSUME_KS(b, 1);
        __builtin_amdgcn_sched_barrier(0);
        __builtin_amdgcn_s_barrier();                 // all waves done reading buf b
        if (c + 3 < c1) STAGE(c + 3, b);              // refill just-freed buffer
        b = (b == 2) ? 0 : b + 1;
    }

    // ---- tail: 28 voxels, block owning the end of the range ----
    if (c1 == NCH && c0 < c1) {
        const int row = tid >> 2, scq = tid & 3;      // cols scq*8 .. +7
        #pragma unroll
        for (int i = 0; i < 8; ++i) {
            const int cl = scq * 8 + i;               // logical col 0..31 (k-step 0)
            float v = (cl < NTAIL) ? fm[(size_t)(pb + row) * NN + NCH * CHV + cl] : 0.0f;
            lds[row * 64 + (cl ^ ((row & 7) << 2))] = __float_as_uint(v);
        }
        if (tid < CHV) {
            int a = (tid < NTAIL) ? atlas[NCH * CHV + tid] : 0;
            lds[AOFFD + tid] = (unsigned)a;
        }
        __syncthreads();
        CONSUME_KS(0, 0);
    }

    // ---- store: partials[x][roi(256, tiles 0..12)][plane(1024)] ----
    // D layout: col = lane&15, row = 4*(lane>>4)+i
    float* pc = partials + (size_t)x * (MROI * NPLANES);
    const int rbase = 4 * g;
    #pragma unroll
    for (int t = 0; t < 4; ++t) {
        if (t < NT) {
            #pragma unroll
            for (int p = 0; p < 4; ++p)
                #pragma unroll
                for (int i = 0; i < 4; ++i)
                    pc[(size_t)((t0 + t) * 16 + rbase + i) * NPLANES + (pb + 16 * p + n)] = acc[t][p][i];
        }
    }
}

// ---------------- finalize: reduce chunks + divide + mask ----------------
__global__ __launch_bounds__(256) void roi_final2(const float* __restrict__ partials,
                                                  const float* __restrict__ counts,
                                                  float* __restrict__ out,
                                                  const int kch) {
    const int j = blockIdx.x * 256 + threadIdx.x;
    if (j < NFEAT) {
        const int c = j & (NC - 1);
        const int r = (j >> 8) % NR;
        const int bb = j / (NR * NC);
        const int plane = bb * NC + c;
        float s = 0.0f;
        for (int ch = 0; ch < kch; ++ch)
            s += partials[((size_t)ch * MROI + r) * NPLANES + plane];
        const float cnt = counts[r];
        out[j] = (cnt > 0.0f) ? s / cnt : 0.0f;
    } else if (j < NFEAT + NB * NR) {
        const int r = (j - NFEAT) % NR;
        out[j] = (counts[r] > 0.0f) ? 1.0f : 0.0f;
    }
}

extern "C" void kernel_launch(void* const* d_in, const int* in_sizes, int n_in,
                              void* d_out, int out_size, void* d_ws, size_t ws_size,
                              hipStream_t stream) {
    const float* fm    = (const float*)d_in[0];
    const int*   atlas = (const int*)d_in[1];
    float*       out   = (float*)d_out;

    float* counts   = (float*)d_ws;     // 256 floats
    float* partials = counts + 256;     // kch * MROI * NPLANES floats

    int kch = 48;                        // 48*16 = 768 blocks = 3/CU exactly
    while (kch > 12 &&
           ws_size < 1024 + (size_t)kch * MROI * NPLANES * sizeof(float))
        kch >>= 1;

    hipMemsetAsync(counts, 0, NR * sizeof(float), stream);

    roi_count<<<(NVEC + 255) / 256, 256, 0, stream>>>(atlas, counts);

    roi_accum_async<<<dim3(kch, 16), 256, 0, stream>>>(fm, atlas, partials);

    const int total = NFEAT + NB * NR;
    roi_final2<<<(total + 255) / 256, 256, 0, stream>>>(partials, counts, out, kch);
}